// Round 3
// baseline (216.027 us; speedup 1.0000x reference)
//
#include <hip/hip_runtime.h>

#define N_NODES 4096
#define FIN     512
#define FOUT    256
#define NSPLIT  4
#define NTILES  ((N_NODES / NSPLIT) / 64)   // 16

typedef __attribute__((ext_vector_type(8))) short bf16x8s;
typedef __attribute__((ext_vector_type(4))) float f32x4;
typedef __attribute__((ext_vector_type(8))) unsigned short u16x8;
typedef unsigned short u16;
typedef unsigned int   u32;

__device__ inline u16 f2b(float f) {
    union { float f; unsigned int u; } v; v.f = f;
    unsigned int r = v.u + 0x7fffu + ((v.u >> 16) & 1u);   // RTNE
    return (u16)(r >> 16);
}

// ---------------------------------------------------------------------------
// prep: [0,1024)    h fp32 -> hb bf16
//       [1024,1088) W_b -> WTb bf16 transposed [n][k]
//       [1088]      zero s1/s2
// ---------------------------------------------------------------------------
__global__ __launch_bounds__(256) void prep_kernel(
    const float* __restrict__ h, const float* __restrict__ Wn,
    const float* __restrict__ Wd,
    u16* __restrict__ hb, u16* __restrict__ WTb, float* __restrict__ s12)
{
    __shared__ u16 tl[64 * 72];
    const int t = threadIdx.x;
    const int bid = blockIdx.x;

    if (bid < 1024) {                       // h convert
        int idx = (bid * 256 + t) * 8;
        float4 f0 = *(const float4*)&h[idx];
        float4 f1 = *(const float4*)&h[idx + 4];
        u16x8 o;
        o[0]=f2b(f0.x); o[1]=f2b(f0.y); o[2]=f2b(f0.z); o[3]=f2b(f0.w);
        o[4]=f2b(f1.x); o[5]=f2b(f1.y); o[6]=f2b(f1.z); o[7]=f2b(f1.w);
        *(u16x8*)&hb[idx] = o;
    } else if (bid < 1088) {                // W transpose+convert, 64x64 tiles
        int id = bid - 1024;
        int kx = id & 7, ny = (id >> 3) & 3, b = id >> 5;
        const float* W = b ? Wd : Wn;
        int k0 = kx * 64, n0 = ny * 64;
        int kr = t >> 2, nc0 = (t & 3) * 16;
        const float* src = W + (size_t)(k0 + kr) * FOUT + n0 + nc0;
        #pragma unroll
        for (int jv = 0; jv < 4; ++jv) {
            float4 f = *(const float4*)(src + jv * 4);
            tl[(nc0 + jv * 4 + 0) * 72 + kr] = f2b(f.x);
            tl[(nc0 + jv * 4 + 1) * 72 + kr] = f2b(f.y);
            tl[(nc0 + jv * 4 + 2) * 72 + kr] = f2b(f.z);
            tl[(nc0 + jv * 4 + 3) * 72 + kr] = f2b(f.w);
        }
        __syncthreads();
        int n = t >> 2, kc0 = (t & 3) * 16;
        u16* dst = WTb + ((size_t)b << 17) + (size_t)(n0 + n) * FIN + k0 + kc0;
        *(uint4*)dst       = *(uint4*)&tl[n * 72 + kc0];
        *(uint4*)(dst + 8) = *(uint4*)&tl[n * 72 + kc0 + 8];
    } else {                                // zero s1,s2 (16384 floats)
        float4 z = {0.f, 0.f, 0.f, 0.f};
        float4* p4 = (float4*)s12;
        #pragma unroll
        for (int k = 0; k < 16; ++k) p4[k * 256 + t] = z;
    }
}

// ---------------------------------------------------------------------------
// wh_gemm: WhT[b][n][i] = (hb @ W_b)[i][n]; epilogue also accumulates
// s1[b][i] += sum_n C[i][n]*a1[n], s2 likewise (atomics across n0-blocks).
// grid (64, 4, 2).
// ---------------------------------------------------------------------------
__global__ __launch_bounds__(256) void wh_gemm_kernel(
    const u16* __restrict__ hb, const u16* __restrict__ WTb,
    const float* __restrict__ a1n, const float* __restrict__ a2n,
    const float* __restrict__ a1d, const float* __restrict__ a2d,
    u16* __restrict__ WhT, float* __restrict__ s1, float* __restrict__ s2)
{
    __shared__ u16 smem[8192];
    u16* a_lds = smem;
    u16* b_lds = smem + 4096;

    const int t = threadIdx.x, lane = t & 63, w = t >> 6;
    const int q = lane >> 4, ln = lane & 15;
    const int i0 = blockIdx.x * 64, n0 = blockIdx.y * 64, b = blockIdx.z;
    const u16* wt = WTb + ((size_t)b << 17);

    f32x4 acc[4];
    #pragma unroll
    for (int i = 0; i < 4; ++i) acc[i] = (f32x4){0.f, 0.f, 0.f, 0.f};

    for (int kt = 0; kt < 8; ++kt) {
        const int k0 = kt * 64;
        __syncthreads();
        #pragma unroll
        for (int it = 0; it < 2; ++it) {
            int chunk = it * 256 + t;
            int r = chunk >> 3, kc = chunk & 7;
            const u16* g = hb + (size_t)(i0 + r) * FIN + k0 + ((kc ^ (r & 7)) * 8);
            u16* l = a_lds + (it * 256 + w * 64) * 8;
            __builtin_amdgcn_global_load_lds(
                (const __attribute__((address_space(1))) void*)g,
                (__attribute__((address_space(3))) void*)l, 16, 0, 0);
        }
        #pragma unroll
        for (int it = 0; it < 2; ++it) {
            int chunk = it * 256 + t;
            int n = chunk >> 3, kc = chunk & 7;
            const u16* g = wt + (size_t)(n0 + n) * FIN + k0 + ((kc ^ (n & 7)) * 8);
            u16* l = b_lds + (it * 256 + w * 64) * 8;
            __builtin_amdgcn_global_load_lds(
                (const __attribute__((address_space(1))) void*)g,
                (__attribute__((address_space(3))) void*)l, 16, 0, 0);
        }
        __syncthreads();
        #pragma unroll
        for (int ks = 0; ks < 2; ++ks) {
            int sw = ((ks * 4 + q) ^ (ln & 7)) * 8;
            bf16x8s af = *(const bf16x8s*)&a_lds[(w * 16 + ln) * 64 + sw];
            #pragma unroll
            for (int nt = 0; nt < 4; ++nt) {
                bf16x8s bfv = *(const bf16x8s*)&b_lds[(nt * 16 + ln) * 64 + sw];
                acc[nt] = __builtin_amdgcn_mfma_f32_16x16x32_bf16(af, bfv, acc[nt], 0, 0, 0);
            }
        }
    }

    {
        const float* a1 = b ? a1d : a1n;
        const float* a2 = b ? a2d : a2n;
        float s1p[4] = {0.f, 0.f, 0.f, 0.f};
        float s2p[4] = {0.f, 0.f, 0.f, 0.f};
        #pragma unroll
        for (int nt = 0; nt < 4; ++nt) {
            float va1 = a1[n0 + nt * 16 + ln];
            float va2 = a2[n0 + nt * 16 + ln];
            #pragma unroll
            for (int r = 0; r < 4; ++r) {
                s1p[r] += acc[nt][r] * va1;
                s2p[r] += acc[nt][r] * va2;
            }
        }
        #pragma unroll
        for (int r = 0; r < 4; ++r) {
            #pragma unroll
            for (int off = 8; off >= 1; off >>= 1) {
                s1p[r] += __shfl_xor(s1p[r], off);
                s2p[r] += __shfl_xor(s2p[r], off);
            }
            if (ln == 0) {
                int row = i0 + w * 16 + q * 4 + r;
                atomicAdd(&s1[b * N_NODES + row], s1p[r]);
                atomicAdd(&s2[b * N_NODES + row], s2p[r]);
            }
        }
    }

    __syncthreads();
    #pragma unroll
    for (int nt = 0; nt < 4; ++nt)
        #pragma unroll
        for (int r = 0; r < 4; ++r)
            smem[(nt * 16 + ln) * 72 + (w * 16 + q * 4 + r)] = f2b(acc[nt][r]);
    __syncthreads();
    {
        const int nl = t >> 2, is = (t & 3) * 16;
        u16* dst = WhT + ((size_t)b << 20) + (size_t)(n0 + nl) * N_NODES + i0 + is;
        *(uint4*)dst       = *(uint4*)&smem[nl * 72 + is];
        *(uint4*)(dst + 8) = *(uint4*)&smem[nl * 72 + is + 8];
    }
}

// ---------------------------------------------------------------------------
// attn: 64 rows x 1024-j per block. SOFTWARE-PIPELINED: P-compute runs one
// tile AHEAD of the MFMA that consumes it (p_lds double-buffered), so the
// exp/VALU work of tile jt+1 and the ds_read+MFMA work of tile jt live in
// the SAME barrier-free region and the scheduler can interleave the two
// pipes. One __syncthreads per tile (was 2). WhT also double-buffered; all
// loads have a full iteration body (~µs) to complete, so no hand vmcnt.
// grid (64, NSPLIT, 2).
// ---------------------------------------------------------------------------
__global__ __launch_bounds__(256) void attn_kernel(
    const int* __restrict__ adj_n, const int* __restrict__ adj_d,
    const u16* __restrict__ WhT,
    const float* __restrict__ s1, const float* __restrict__ s2,
    float* __restrict__ num_ws, float* __restrict__ den_ws)
{
    __shared__ u16 wht_lds[2][256 * 64];   // 2 x 32 KB
    __shared__ u16 p_lds[2][64 * 64];      // 2 x 8 KB

    const int t = threadIdx.x, lane = t & 63, w = t >> 6;
    const int q = lane >> 4, ln = lane & 15;
    const int b = blockIdx.z, split = blockIdx.y;
    const int i0 = blockIdx.x * 64;

    const int* adjb = b ? adj_d : adj_n;
    const u16* whtB = WhT + ((size_t)b << 20);
    const float* s1b = s1 + b * N_NODES;
    const float* s2b = s2 + b * N_NODES;

    const int pr = t >> 3;              // P row 0..31 (also handles pr+32)
    const int cw = t & 7;               // P k-chunk 0..7
    const int pc = cw * 8;
    const float s1v0 = s1b[i0 + pr];
    const float s1v1 = s1b[i0 + pr + 32];
    const size_t arow0 = (size_t)(i0 + pr) * N_NODES + pc;
    const size_t arow1 = arow0 + (size_t)32 * N_NODES;
    const int swp = (cw ^ (pr & 7)) * 8;

    float den0 = 0.f, den1 = 0.f;       // full sums live on (t&7)==0 threads

    f32x4 acc[4][4];
    #pragma unroll
    for (int mt = 0; mt < 4; ++mt)
        #pragma unroll
        for (int nt = 0; nt < 4; ++nt) acc[mt][nt] = (f32x4){0.f, 0.f, 0.f, 0.f};

    const int jbase = split * (N_NODES / NSPLIT);

#define STAGE_WHT(BUF, J0) do {                                               \
    _Pragma("unroll")                                                         \
    for (int it_ = 0; it_ < 8; ++it_) {                                       \
        int chunk_ = it_ * 256 + t;                                           \
        int n_ = chunk_ >> 3, kc_ = chunk_ & 7;                               \
        const u16* g_ = whtB + (size_t)n_ * N_NODES + (J0) + ((kc_ ^ (n_ & 7)) * 8); \
        u16* l_ = &wht_lds[BUF][(it_ * 256 + w * 64) * 8];                    \
        __builtin_amdgcn_global_load_lds(                                     \
            (const __attribute__((address_space(1))) void*)g_,                \
            (__attribute__((address_space(3))) void*)l_, 16, 0, 0);           \
    } } while (0)

#define P_COMPUTE(BUF, A00, A01, A10, A11, SV0, SV1) do {                     \
    int v0_[8] = {(A00).x, (A00).y, (A00).z, (A00).w,                         \
                  (A01).x, (A01).y, (A01).z, (A01).w};                        \
    int v1_[8] = {(A10).x, (A10).y, (A10).z, (A10).w,                         \
                  (A11).x, (A11).y, (A11).z, (A11).w};                        \
    float sv_[8] = {(SV0).x, (SV0).y, (SV0).z, (SV0).w,                       \
                    (SV1).x, (SV1).y, (SV1).z, (SV1).w};                      \
    float d0_ = 0.f, d1_ = 0.f;                                               \
    u16x8 pk0_, pk1_;                                                         \
    _Pragma("unroll")                                                         \
    for (int jj_ = 0; jj_ < 8; ++jj_) {                                       \
        float sv_j = sv_[jj_];                                                \
        float x0_ = s1v0 + sv_j, x1_ = s1v1 + sv_j;                           \
        float p0_ = (v0_[jj_] > 0) ? __expf(fmaxf(x0_, 0.2f * x0_)) : 0.f;    \
        float p1_ = (v1_[jj_] > 0) ? __expf(fmaxf(x1_, 0.2f * x1_)) : 0.f;    \
        d0_ += p0_; d1_ += p1_;                                               \
        pk0_[jj_] = f2b(p0_); pk1_[jj_] = f2b(p1_);                           \
    }                                                                         \
    d0_ += __shfl_down(d0_, 4, 8); d1_ += __shfl_down(d1_, 4, 8);             \
    d0_ += __shfl_down(d0_, 2, 8); d1_ += __shfl_down(d1_, 2, 8);             \
    d0_ += __shfl_down(d0_, 1, 8); d1_ += __shfl_down(d1_, 1, 8);             \
    den0 += d0_; den1 += d1_;                                                 \
    *(u16x8*)&p_lds[BUF][pr * 64 + swp] = pk0_;                               \
    *(u16x8*)&p_lds[BUF][(pr + 32) * 64 + swp] = pk1_;                        \
} while (0)

#define MFMA_TILE(BUF) do {                                                   \
    _Pragma("unroll")                                                         \
    for (int ks_ = 0; ks_ < 2; ++ks_) {                                       \
        int sw_ = ((ks_ * 4 + q) ^ (ln & 7)) * 8;                             \
        bf16x8s af0_ = *(const bf16x8s*)&p_lds[BUF][(0 * 16 + ln) * 64 + sw_];\
        bf16x8s af1_ = *(const bf16x8s*)&p_lds[BUF][(1 * 16 + ln) * 64 + sw_];\
        bf16x8s af2_ = *(const bf16x8s*)&p_lds[BUF][(2 * 16 + ln) * 64 + sw_];\
        bf16x8s af3_ = *(const bf16x8s*)&p_lds[BUF][(3 * 16 + ln) * 64 + sw_];\
        _Pragma("unroll")                                                     \
        for (int nt_ = 0; nt_ < 4; ++nt_) {                                   \
            bf16x8s bfv_ = *(const bf16x8s*)&wht_lds[BUF][(w * 64 + nt_ * 16 + ln) * 64 + sw_]; \
            acc[0][nt_] = __builtin_amdgcn_mfma_f32_16x16x32_bf16(af0_, bfv_, acc[0][nt_], 0, 0, 0); \
            acc[1][nt_] = __builtin_amdgcn_mfma_f32_16x16x32_bf16(af1_, bfv_, acc[1][nt_], 0, 0, 0); \
            acc[2][nt_] = __builtin_amdgcn_mfma_f32_16x16x32_bf16(af2_, bfv_, acc[2][nt_], 0, 0, 0); \
            acc[3][nt_] = __builtin_amdgcn_mfma_f32_16x16x32_bf16(af3_, bfv_, acc[3][nt_], 0, 0, 0); \
        }                                                                     \
    } } while (0)

    // ---- prologue: stage+P tile 0, prefetch adj/s2 of tile 1 ----
    STAGE_WHT(0, jbase);
    int4 c00 = *(const int4*)&adjb[arow0 + jbase];
    int4 c01 = *(const int4*)&adjb[arow0 + jbase + 4];
    int4 c10 = *(const int4*)&adjb[arow1 + jbase];
    int4 c11 = *(const int4*)&adjb[arow1 + jbase + 4];
    float4 cs0 = *(const float4*)&s2b[jbase + pc];
    float4 cs1 = *(const float4*)&s2b[jbase + pc + 4];
    int4 a00_pf = *(const int4*)&adjb[arow0 + jbase + 64];
    int4 a01_pf = *(const int4*)&adjb[arow0 + jbase + 64 + 4];
    int4 a10_pf = *(const int4*)&adjb[arow1 + jbase + 64];
    int4 a11_pf = *(const int4*)&adjb[arow1 + jbase + 64 + 4];
    float4 sv0_pf = *(const float4*)&s2b[jbase + 64 + pc];
    float4 sv1_pf = *(const float4*)&s2b[jbase + 64 + pc + 4];
    P_COMPUTE(0, c00, c01, c10, c11, cs0, cs1);
    __syncthreads();   // tile0: wht_lds[0] staged, p_lds[0] written

    // ---- main loop: P(jt+1) + MFMA(jt) share one barrier-free region ----
    for (int jt = 0; jt < NTILES - 1; ++jt) {
        const int cur = jt & 1, nxt = cur ^ 1;
        STAGE_WHT(nxt, jbase + (jt + 1) * 64);
        c00 = a00_pf; c01 = a01_pf; c10 = a10_pf; c11 = a11_pf;
        cs0 = sv0_pf; cs1 = sv1_pf;
        {
            const int j2 = jbase + ((jt + 2 < NTILES) ? jt + 2 : NTILES - 1) * 64;
            a00_pf = *(const int4*)&adjb[arow0 + j2];
            a01_pf = *(const int4*)&adjb[arow0 + j2 + 4];
            a10_pf = *(const int4*)&adjb[arow1 + j2];
            a11_pf = *(const int4*)&adjb[arow1 + j2 + 4];
            sv0_pf = *(const float4*)&s2b[j2 + pc];
            sv1_pf = *(const float4*)&s2b[j2 + pc + 4];
        }
        P_COMPUTE(nxt, c00, c01, c10, c11, cs0, cs1);   // tile jt+1 -> p_lds[nxt]
        MFMA_TILE(cur);                                 // tile jt   <- p_lds[cur]
        __syncthreads();
    }
    MFMA_TILE((NTILES - 1) & 1);                        // last tile

#undef STAGE_WHT
#undef P_COMPUTE
#undef MFMA_TILE

    const size_t pbase = (size_t)(b * NSPLIT + split) * N_NODES;
    #pragma unroll
    for (int mt = 0; mt < 4; ++mt)
        #pragma unroll
        for (int r = 0; r < 4; ++r) {
            int row = mt * 16 + q * 4 + r;
            #pragma unroll
            for (int nt = 0; nt < 4; ++nt)
                num_ws[(pbase + i0 + row) * FOUT + w * 64 + nt * 16 + ln] = acc[mt][nt][r];
        }
    if ((t & 7) == 0) {
        den_ws[pbase + i0 + pr] = den0;
        den_ws[pbase + i0 + pr + 32] = den1;
    }
}

// ---------------------------------------------------------------------------
// reduce: sum splits, elu(num/den), merge branches.
// ---------------------------------------------------------------------------
__global__ __launch_bounds__(256) void reduce_kernel(
    const float* __restrict__ num_ws, const float* __restrict__ den_ws,
    float* __restrict__ out)
{
    int gid = blockIdx.x * 256 + threadIdx.x;
    int i = gid >> 6;
    int f4 = (gid & 63) * 4;
    float4 o = {0.f, 0.f, 0.f, 0.f};
    #pragma unroll
    for (int b = 0; b < 2; ++b) {
        float4 num = {0.f, 0.f, 0.f, 0.f};
        float den = 0.f;
        #pragma unroll
        for (int s = 0; s < NSPLIT; ++s) {
            const float4 v = *(const float4*)&num_ws[((size_t)(b * NSPLIT + s) * N_NODES + i) * FOUT + f4];
            num.x += v.x; num.y += v.y; num.z += v.z; num.w += v.w;
            den += den_ws[(size_t)(b * NSPLIT + s) * N_NODES + i];
        }
        float inv = 1.0f / den;
        float e0 = num.x * inv, e1 = num.y * inv, e2 = num.z * inv, e3 = num.w * inv;
        o.x += (e0 > 0.f) ? e0 : expm1f(e0);
        o.y += (e1 > 0.f) ? e1 : expm1f(e1);
        o.z += (e2 > 0.f) ? e2 : expm1f(e2);
        o.w += (e3 > 0.f) ? e3 : expm1f(e3);
    }
    *(float4*)&out[(size_t)i * FOUT + f4] = o;
}

extern "C" void kernel_launch(void* const* d_in, const int* in_sizes, int n_in,
                              void* d_out, int out_size, void* d_ws, size_t ws_size,
                              hipStream_t stream) {
    const float* h    = (const float*)d_in[0];
    const int*   adjn = (const int*)d_in[1];
    const int*   adjd = (const int*)d_in[2];
    const float* Wn   = (const float*)d_in[4];
    const float* a1n  = (const float*)d_in[5];
    const float* a2n  = (const float*)d_in[6];
    const float* Wd   = (const float*)d_in[7];
    const float* a1d  = (const float*)d_in[8];
    const float* a2d  = (const float*)d_in[9];

    char* ws = (char*)d_ws;
    // [0,4M): WhT   [4M,8M): (free)   [8M,8M+192K): s1,s2,den
    // [8.25M,12.25M): hb   [12.25M,12.75M): WTb   (dead after wh_gemm)
    // [8.25M,40.25M): num  (overlays hb/WTb; written by attn after wh_gemm)
    u16*  WhT  = (u16*)ws;
    float* s1  = (float*)(ws + ((size_t)8 << 20));
    float* s2  = s1 + 2 * N_NODES;
    float* den = s2 + 2 * N_NODES;
    u16*  hb   = (u16*)(ws + ((size_t)8 << 20) + ((size_t)256 << 10));
    u16*  WTb  = (u16*)(ws + ((size_t)12 << 20) + ((size_t)256 << 10));
    float* num = (float*)(ws + ((size_t)8 << 20) + ((size_t)256 << 10));

    prep_kernel<<<1089, 256, 0, stream>>>(h, Wn, Wd, hb, WTb, s1);
    wh_gemm_kernel<<<dim3(64, 4, 2), 256, 0, stream>>>(hb, WTb, a1n, a2n, a1d, a2d, WhT, s1, s2);
    attn_kernel<<<dim3(64, NSPLIT, 2), 256, 0, stream>>>(adjn, adjd, WhT, s1, s2, num, den);
    reduce_kernel<<<1024, 256, 0, stream>>>(num, den, (float*)d_out);
}